// Round 10
// baseline (937.244 us; speedup 1.0000x reference)
//
#include <hip/hip_runtime.h>
#include <hip/hip_bf16.h>
#include <hip/hip_fp16.h>
#include <math.h>

#define NL 4
#define DM 1024
#define DI 2048
#define DS 16
#define DR 64
#define DC 4
#define B_ 8
#define L_ 224
#define DLOC 672
#define NC 10
#define EPS 1e-5f

#define ROWS (B_ * L_)  // 1792
#define NCHK 14         // time chunks for parallel scan
#define CHS 16          // steps per chunk (14*16 = 224 = L_)

typedef unsigned short u16;
typedef __attribute__((ext_vector_type(8))) short bf16x8;
typedef __attribute__((ext_vector_type(4))) float f32x4;
typedef __attribute__((address_space(1))) const void gvoid_t;
typedef __attribute__((address_space(3))) void lvoid_t;

__device__ __forceinline__ u16 f2bf(float f) {
  union { float f; unsigned int u; } v;
  v.f = f;
  unsigned int u = v.u;
  return (u16)((u + 0x7fffu + ((u >> 16) & 1u)) >> 16);  // RNE
}

// load 4 consecutive halfs (8B aligned) -> 4 floats
__device__ __forceinline__ void load4h(const __half* p, float* o) {
  uint2 r = *(const uint2*)p;
  __half2 h0 = *(__half2*)&r.x;
  __half2 h1 = *(__half2*)&r.y;
  float2 f0 = __half22float2(h0);
  float2 f1 = __half22float2(h1);
  o[0] = f0.x; o[1] = f0.y; o[2] = f1.x; o[3] = f1.y;
}

// ---------------------------------------------------------------------------
// bf16 MFMA GEMM: C[M,N](+)=A[M,K]_bf16 @ Bt[N,K]_bf16^T. 128x128 tile.
// 2-phase pipeline, zero-asm: double-buffered LDS; STAGE(t+1) issued BEFORE
// computing tile t; single __syncthreads() per K-step.
// ACC: 0=store, 1=+=, 2=atomicAdd(float). BROW: 0 none, 1 bias[n-col],
// 2 bias[m-row]. TSTORE=1: store C^T fp16 (OT=__half). ACT=1: softplus.
// SPLITK: nonzero = per-z K-chunk size in elements (K arg = chunk size).
// fp16 outputs (OT=__half) use an LDS-staged coalesced epilogue: acc values
// (bias/ACT applied in-register) are staged into the dead As/Bs 32KB as a
// 128x128 half tile (XOR-16B swizzle), then written back as linear 16B
// stores — replaces 64 scattered 2-8B stores/thread.
// ---------------------------------------------------------------------------
template <int ACC, int BROW, int TSTORE, int ACT, int SPLITK, typename OT>
__global__ __launch_bounds__(256) void gemm_bt_mfma(
    const u16* __restrict__ A, const u16* __restrict__ Bt,
    const float* __restrict__ bias, OT* __restrict__ C, int K, int lda,
    int ldb, int ldc) {
  if (SPLITK) {
    A += (size_t)blockIdx.z * SPLITK;
    Bt += (size_t)blockIdx.z * SPLITK;
  }
  __shared__ __align__(16) u16 As[2][128 * 32];
  __shared__ __align__(16) u16 Bs[2][128 * 32];
  const int tid = threadIdx.x;
  const int lane = tid & 63;
  const int wv = tid >> 6;
  const int n0 = blockIdx.x * 128;
  const int m0 = blockIdx.y * 128;
  const int wm0 = (wv & 1) * 64;
  const int wn0 = (wv >> 1) * 64;
  const int quad = lane >> 4;
  const int l16 = lane & 15;

  const int srow = wv * 32 + (lane >> 2);
  const int scol = (lane & 3) * 8;
  const u16* ga0 = A + (size_t)(m0 + srow) * lda + scol;
  const u16* ga1 = ga0 + (size_t)16 * lda;
  const u16* gb0 = Bt + (size_t)(n0 + srow) * ldb + scol;
  const u16* gb1 = gb0 + (size_t)16 * ldb;
  const int lo0 = (wv * 32) * 32;
  const int lo1 = (wv * 32 + 16) * 32;

  f32x4 acc[4][4] = {};

  auto STAGE = [&](int buf, int kk) {
    __builtin_amdgcn_global_load_lds((gvoid_t*)(ga0 + kk),
                                     (lvoid_t*)&As[buf][lo0], 16, 0, 0);
    __builtin_amdgcn_global_load_lds((gvoid_t*)(ga1 + kk),
                                     (lvoid_t*)&As[buf][lo1], 16, 0, 0);
    __builtin_amdgcn_global_load_lds((gvoid_t*)(gb0 + kk),
                                     (lvoid_t*)&Bs[buf][lo0], 16, 0, 0);
    __builtin_amdgcn_global_load_lds((gvoid_t*)(gb1 + kk),
                                     (lvoid_t*)&Bs[buf][lo1], 16, 0, 0);
  };

  const int NT = K >> 5;
  STAGE(0, 0);
  __syncthreads();
  for (int t = 0; t < NT; ++t) {
    const int cur = t & 1;
    if (t + 1 < NT) STAGE(cur ^ 1, (t + 1) << 5);
    bf16x8 af[4], bfr[4];
#pragma unroll
    for (int i = 0; i < 4; i++)
      af[i] = *(const bf16x8*)&As[cur][(wm0 + i * 16 + l16) * 32 + quad * 8];
#pragma unroll
    for (int j = 0; j < 4; j++)
      bfr[j] = *(const bf16x8*)&Bs[cur][(wn0 + j * 16 + l16) * 32 + quad * 8];
#pragma unroll
    for (int i = 0; i < 4; i++)
#pragma unroll
      for (int j = 0; j < 4; j++)
        acc[i][j] = __builtin_amdgcn_mfma_f32_16x16x32_bf16(af[i], bfr[j],
                                                            acc[i][j], 0, 0, 0);
    // drains staged loads (overlapped with the MFMA above) + read-done fence
    __syncthreads();
  }

  if constexpr (sizeof(OT) == 2) {
    // ---- LDS-staged coalesced fp16 epilogue (As/Bs dead after K-loop) ----
    // Logical tile [A][Bc]: A = output-row-local, Bc = output-col-local.
    // TSTORE=1: output C^T -> A=n_local, Bc=m_local. Else row-major.
    // Swizzle: physical 16B-chunk index = (Bc>>3) ^ (A&7); rows 0-63 in As,
    // 64-127 in Bs (each exactly 64*128 halfs = 16KB).
    u16* tb = ((TSTORE ? wn0 : wm0) == 0) ? (u16*)As : (u16*)Bs;
#pragma unroll
    for (int i = 0; i < 4; i++) {
#pragma unroll
      for (int j = 0; j < 4; j++) {
#pragma unroll
        for (int r = 0; r < 4; r++) {
          const int ml = wm0 + i * 16 + quad * 4 + r;
          const int nl = wn0 + j * 16 + l16;
          const int Aa = TSTORE ? nl : ml;
          const int Bc = TSTORE ? ml : nl;
          float v = acc[i][j][r];
          if (BROW == 1) v += bias[n0 + nl];
          if (BROW == 2) v += bias[m0 + ml];
          if (ACT == 1) v = (v > 20.f) ? v : log1pf(expf(v));  // softplus
          const int phys = (((Bc >> 3) ^ (Aa & 7)) << 3) + (Bc & 7);
          tb[(Aa & 63) * 128 + phys] = __half_as_ushort(__float2half(v));
        }
      }
    }
    __syncthreads();
    // linear writeback: thread t covers row t>>1, 16B chunks (t&1)*8+k
    const int row = tid >> 1;
    const u16* src = (row < 64) ? (const u16*)As : (const u16*)Bs;
    const int r6 = row & 63;
    __half* Ch = (__half*)C;
#pragma unroll
    for (int k = 0; k < 8; k++) {
      const int phys16 = (tid & 1) * 8 + k;
      const int log16 = phys16 ^ (row & 7);
      const uint4 val = *(const uint4*)&src[r6 * 128 + phys16 * 8];
      __half* dst = TSTORE
          ? (Ch + (size_t)(n0 + row) * ldc + m0 + log16 * 8)
          : (Ch + (size_t)(m0 + row) * ldc + n0 + log16 * 8);
      *(uint4*)dst = val;
    }
  } else {
#pragma unroll
    for (int i = 0; i < 4; i++) {
#pragma unroll
      for (int j = 0; j < 4; j++) {
        const int col = n0 + wn0 + j * 16 + l16;
        const int rowb = m0 + wm0 + i * 16 + quad * 4;
        float bv = 0.f;
        if (BROW == 1) bv = bias[col];
#pragma unroll
        for (int r = 0; r < 4; r++) {
          float v = acc[i][j][r] + bv;
          if (BROW == 2) v += bias[rowb + r];
          if (ACT == 1) v = (v > 20.f) ? v : log1pf(expf(v));  // softplus
          OT* p = C + (size_t)(rowb + r) * ldc + col;
          if (ACC == 2) {
            atomicAdd((float*)p, v);
          } else {
            if (ACC == 1) v += (float)*p;
            *p = (OT)v;
          }
        }
      }
    }
  }
}

// ---------------------------------------------------------------------------
// fp32 [K,N] -> bf16 [N,K] transpose+convert (32x32 tiles)
// ---------------------------------------------------------------------------
__device__ __forceinline__ void transpose_cvt_body(
    const float* __restrict__ src, u16* __restrict__ dst, int K, int N,
    int bx, int by, int tid) {
  __shared__ float t[32][33];
  const int n0 = bx * 32;
  const int k0 = by * 32;
  const int c = tid & 31;
  const int r = tid >> 5;
#pragma unroll
  for (int rr = 0; rr < 4; rr++)
    t[r + rr * 8][c] = src[(size_t)(k0 + r + rr * 8) * N + n0 + c];
  __syncthreads();
#pragma unroll
  for (int rr = 0; rr < 4; rr++)
    dst[(size_t)(n0 + r + rr * 8) * K + k0 + c] = f2bf(t[c][r + rr * 8]);
}

__global__ __launch_bounds__(256) void transpose_cvt_kernel(
    const float* __restrict__ src, u16* __restrict__ dst, int K, int N) {
  transpose_cvt_body(src, dst, K, N, blockIdx.x, blockIdx.y, threadIdx.x);
}

// All per-layer weight transposes in ONE launch.
// blocks: [0,4096) winT, [4096,6144) woutT, [6144,6336) w_x16, [6336,6464) w_dt16
__global__ __launch_bounds__(256) void prep_weights_kernel(
    const float* __restrict__ w_in_l, const float* __restrict__ w_out_l,
    const float* __restrict__ w_x_l, const float* __restrict__ w_dt_l,
    u16* __restrict__ winT, u16* __restrict__ woutT, u16* __restrict__ w_x16,
    u16* __restrict__ w_dt16) {
  int bid = blockIdx.x;
  if (bid < 4096) {
    transpose_cvt_body(w_in_l, winT, DM, 2 * DI, bid & 127, bid >> 7,
                       threadIdx.x);
  } else if (bid < 6144) {
    bid -= 4096;
    transpose_cvt_body(w_out_l, woutT, DI, DM, bid & 31, bid >> 5,
                       threadIdx.x);
  } else if (bid < 6336) {
    bid -= 6144;
    transpose_cvt_body(w_x_l, w_x16, DI, 96, bid % 3, bid / 3, threadIdx.x);
  } else {
    bid -= 6336;
    transpose_cvt_body(w_dt_l, w_dt16, DR, DI, bid & 63, bid >> 6,
                       threadIdx.x);
  }
}

// flat fp32 -> bf16
__global__ __launch_bounds__(256) void cvt_kernel(const float* __restrict__ src,
                                                  u16* __restrict__ dst) {
  const int i = blockIdx.x * 256 + threadIdx.x;
  const float4 v = ((const float4*)src)[i];
  ushort4 o;
  o.x = f2bf(v.x);
  o.y = f2bf(v.y);
  o.z = f2bf(v.z);
  o.w = f2bf(v.w);
  ((ushort4*)dst)[i] = o;
}

// h[row][col] = b_proj[col]  (pre-fill for split-K atomic proj GEMM)
__global__ __launch_bounds__(256) void init_bias_kernel(
    const float* __restrict__ b, float* __restrict__ h) {
  const int i = blockIdx.x * 256 + threadIdx.x;
  const float4 v = ((const float4*)b)[i & (DM / 4 - 1)];
  ((float4*)h)[i] = v;
}

// ---------------------------------------------------------------------------
// RMSNorm -> bf16
// ---------------------------------------------------------------------------
__global__ __launch_bounds__(256) void rmsnorm_kernel(
    const float* __restrict__ h, const float* __restrict__ w,
    u16* __restrict__ out) {
  const int row = blockIdx.x;
  const int tid = threadIdx.x;
  const float4 v = *(const float4*)(h + (size_t)row * DM + tid * 4);
  float ss = v.x * v.x + v.y * v.y + v.z * v.z + v.w * v.w;
#pragma unroll
  for (int off = 32; off > 0; off >>= 1) ss += __shfl_xor(ss, off);
  __shared__ float red[4];
  if ((tid & 63) == 0) red[tid >> 6] = ss;
  __syncthreads();
  float tot = red[0] + red[1] + red[2] + red[3];
  const float inv = rsqrtf(tot / (float)DM + EPS);
  const float4 wv = *(const float4*)(w + tid * 4);
  ushort4 o;
  o.x = f2bf(v.x * inv * wv.x);
  o.y = f2bf(v.y * inv * wv.y);
  o.z = f2bf(v.z * inv * wv.z);
  o.w = f2bf(v.w * inv * wv.w);
  *(ushort4*)(out + (size_t)row * DM + tid * 4) = o;
}

// ---------------------------------------------------------------------------
// Causal conv + bias + silu, 32x32 tile. Outputs BOTH:
//   uT fp16 [d][row] (for scan)  and  u16rm bf16 [row][d] (for w_x MFMA).
// ---------------------------------------------------------------------------
__global__ __launch_bounds__(256) void conv_silu_tile_kernel(
    const __half* __restrict__ xpT, const float* __restrict__ wc,
    const float* __restrict__ bc, __half* __restrict__ uT,
    u16* __restrict__ u16rm) {
  __shared__ u16 tile[32][33];  // [r-local][d-local] bf16
  const int tid = threadIdx.x;
  const int d0 = blockIdx.x * 32;
  const int r0 = blockIdx.y * 32;  // 32 | 224 => tile within one batch
  const int dl = tid >> 3;
  const int rq = (tid & 7) * 4;
  const int d = d0 + dl;
  const int r = r0 + rq;
  const int t = r % L_;
  const __half* row = xpT + (size_t)d * ROWS + r;
  float v[4];
  load4h(row, v);
  float p0 = 0.f, p1 = 0.f, p2 = 0.f;
  if (t > 0) {
    p0 = __half2float(row[-3]);
    p1 = __half2float(row[-2]);
    p2 = __half2float(row[-1]);
  }
  const float w0 = wc[d * 4 + 0], w1 = wc[d * 4 + 1], w2 = wc[d * 4 + 2],
              w3 = wc[d * 4 + 3];
  const float bb = bc[d];
  float o[4];
  float s;
  s = bb + p0 * w0 + p1 * w1 + p2 * w2 + v[0] * w3; o[0] = s / (1.f + expf(-s));
  s = bb + p1 * w0 + p2 * w1 + v[0] * w2 + v[1] * w3; o[1] = s / (1.f + expf(-s));
  s = bb + p2 * w0 + v[0] * w1 + v[1] * w2 + v[2] * w3; o[2] = s / (1.f + expf(-s));
  s = bb + v[0] * w0 + v[1] * w1 + v[2] * w2 + v[3] * w3; o[3] = s / (1.f + expf(-s));
  union { __half2 h[2]; uint2 u; } pk;
  pk.h[0].x = __float2half(o[0]); pk.h[0].y = __float2half(o[1]);
  pk.h[1].x = __float2half(o[2]); pk.h[1].y = __float2half(o[3]);
  *(uint2*)(uT + (size_t)d * ROWS + r) = pk.u;
#pragma unroll
  for (int i = 0; i < 4; i++) tile[rq + i][dl] = f2bf(o[i]);
  __syncthreads();
  const int rl = tid >> 3;
  const int dq = (tid & 7) * 4;
  ushort4 ov;
  ov.x = tile[rl][dq + 0];
  ov.y = tile[rl][dq + 1];
  ov.z = tile[rl][dq + 2];
  ov.w = tile[rl][dq + 3];
  *(ushort4*)(u16rm + (size_t)(r0 + rl) * DI + d0 + dq) = ov;
}

// ---------------------------------------------------------------------------
// Parallel linear scan, 3 phases, consuming TRANSPOSED tensors
// (dtT/uT/zT [d][row]: each lane's 16 timesteps are 32B contiguous).
// lane = channel (64 ch/wave), 16 states in registers, B/C broadcast via LDS.
// ---------------------------------------------------------------------------
__global__ __launch_bounds__(64) void scan_state_kernel(
    const __half* __restrict__ dtT, const __half* __restrict__ uT,
    const float* __restrict__ xdblT, const float* __restrict__ A_log,
    float* __restrict__ S, float* __restrict__ sumdt) {
  __shared__ float Bsh[CHS][20];  // [t][s], row stride 80B (16B-aligned)
  const int lane = threadIdx.x;
  const int c = blockIdx.x, g = blockIdx.y, b = blockIdx.z;
  const int d = (g << 6) + lane;
  const size_t tbase = (size_t)d * ROWS + (size_t)b * L_ + c * CHS;
  union HU { uint4 v[2]; __half h[16]; };
  HU dtb, ub;
  dtb.v[0] = *(const uint4*)(dtT + tbase);
  dtb.v[1] = *(const uint4*)(dtT + tbase + 8);
  ub.v[0] = *(const uint4*)(uT + tbase);
  ub.v[1] = *(const uint4*)(uT + tbase + 8);
  {
    const int s = lane >> 2, t0 = (lane & 3) * 4;
    const float4 bv = *(const float4*)(xdblT + (size_t)(DR + s) * ROWS +
                                       (size_t)b * L_ + c * CHS + t0);
    Bsh[t0 + 0][s] = bv.x;
    Bsh[t0 + 1][s] = bv.y;
    Bsh[t0 + 2][s] = bv.z;
    Bsh[t0 + 3][s] = bv.w;
  }
  float A2[DS];
  const float* al = A_log + (size_t)d * DS;
#pragma unroll
  for (int s = 0; s < DS; s++) A2[s] = -expf(al[s]) * 1.44269504f;
  __syncthreads();

  float hs[DS];
#pragma unroll
  for (int s = 0; s < DS; s++) hs[s] = 0.f;
  float cd = 0.f;
#pragma unroll
  for (int t = 0; t < CHS; t++) {
    const float dtv = __half2float(dtb.h[t]);
    const float uu = __half2float(ub.h[t]);
    const float du = dtv * uu;
    cd += dtv;
    const float4 B0 = *(const float4*)&Bsh[t][0];
    const float4 B1 = *(const float4*)&Bsh[t][4];
    const float4 B2 = *(const float4*)&Bsh[t][8];
    const float4 B3 = *(const float4*)&Bsh[t][12];
    auto upd = [&](int s0, float4 Bq) {
      hs[s0 + 0] = fmaf(hs[s0 + 0], exp2f(dtv * A2[s0 + 0]), du * Bq.x);
      hs[s0 + 1] = fmaf(hs[s0 + 1], exp2f(dtv * A2[s0 + 1]), du * Bq.y);
      hs[s0 + 2] = fmaf(hs[s0 + 2], exp2f(dtv * A2[s0 + 2]), du * Bq.z);
      hs[s0 + 3] = fmaf(hs[s0 + 3], exp2f(dtv * A2[s0 + 3]), du * Bq.w);
    };
    upd(0, B0); upd(4, B1); upd(8, B2); upd(12, B3);
  }
  float* Sp = S + (((size_t)c * B_ + b) * DI + d) * DS;
#pragma unroll
  for (int s = 0; s < DS; s++) Sp[s] = hs[s];
  sumdt[((size_t)c * B_ + b) * DI + d] = cd;
}

__global__ __launch_bounds__(256) void scan_combine_kernel(
    float* __restrict__ S, const float* __restrict__ sumdt,
    const float* __restrict__ A_log) {
  const int idx = blockIdx.x * 256 + threadIdx.x;  // B_*DI*DS threads
  const int s = idx & 15;
  const int d = (idx >> 4) & (DI - 1);
  const int b = idx >> 15;
  const float A2 = -expf(A_log[(size_t)d * DS + s]) * 1.44269504f;
  float hv = 0.f;
#pragma unroll
  for (int c = 0; c < NCHK; c++) {
    const size_t base = ((size_t)c * B_ + b) * DI + d;
    const size_t ix = base * DS + s;
    const float Sc = S[ix];
    const float Dc = exp2f(A2 * sumdt[base]);
    S[ix] = hv;  // hs_in for chunk c
    hv = fmaf(Dc, hv, Sc);
  }
}

__global__ __launch_bounds__(64) void scan_apply_kernel(
    const __half* __restrict__ dtT, const __half* __restrict__ uT,
    const __half* __restrict__ zT, const float* __restrict__ xdblT,
    const float* __restrict__ A_log, const float* __restrict__ Dp,
    const float* __restrict__ HS, u16* __restrict__ y16) {
  __shared__ float bcs[CHS][36];   // [t][s: 0..15=B, 16..31=C], 144B rows
  __shared__ u16 ytile[CHS][72];   // [t][d-local], padded
  const int lane = threadIdx.x;
  const int c = blockIdx.x, g = blockIdx.y, b = blockIdx.z;
  const int d = (g << 6) + lane;
  const size_t tbase = (size_t)d * ROWS + (size_t)b * L_ + c * CHS;
  union HU { uint4 v[2]; __half h[16]; };
  HU dtb, ub, zb;
  dtb.v[0] = *(const uint4*)(dtT + tbase);
  dtb.v[1] = *(const uint4*)(dtT + tbase + 8);
  ub.v[0] = *(const uint4*)(uT + tbase);
  ub.v[1] = *(const uint4*)(uT + tbase + 8);
  zb.v[0] = *(const uint4*)(zT + tbase);
  zb.v[1] = *(const uint4*)(zT + tbase + 8);
  {
    const int s = lane >> 1, t0 = (lane & 1) * 8;
    const float* src =
        xdblT + (size_t)(DR + s) * ROWS + (size_t)b * L_ + c * CHS + t0;
    const float4 v0 = *(const float4*)src;
    const float4 v1 = *(const float4*)(src + 4);
    bcs[t0 + 0][s] = v0.x; bcs[t0 + 1][s] = v0.y;
    bcs[t0 + 2][s] = v0.z; bcs[t0 + 3][s] = v0.w;
    bcs[t0 + 4][s] = v1.x; bcs[t0 + 5][s] = v1.y;
    bcs[t0 + 6][s] = v1.z; bcs[t0 + 7][s] = v1.w;
  }
  float A2[DS];
  const float* al = A_log + (size_t)d * DS;
#pragma unroll
  for (int s = 0; s < DS; s++) A2[s] = -expf(al[s]) * 1.44269504f;
  float hs[DS];
  const float* hp = HS + (((size_t)c * B_ + b) * DI + d) * DS;
#pragma unroll
  for (int s = 0; s < DS; s++) hs[s] = hp[s];
  const float Dpd = Dp[d];
  __syncthreads();

#pragma unroll
  for (int t = 0; t < CHS; t++) {
    const float dtv = __half2float(dtb.h[t]);
    const float uu = __half2float(ub.h[t]);
    const float zz = __half2float(zb.h[t]);
    const float du = dtv * uu;
    const float4 B0 = *(const float4*)&bcs[t][0];
    const float4 B1 = *(const float4*)&bcs[t][4];
    const float4 B2 = *(const float4*)&bcs[t][8];
    const float4 B3 = *(const float4*)&bcs[t][12];
    const float4 C0 = *(const float4*)&bcs[t][16];
    const float4 C1 = *(const float4*)&bcs[t][20];
    const float4 C2 = *(const float4*)&bcs[t][24];
    const float4 C3 = *(const float4*)&bcs[t][28];
    float p0 = 0.f, p1 = 0.f, p2 = 0.f, p3 = 0.f;
    auto upd = [&](int s0, float4 Bq, float4 Cq) {
      hs[s0 + 0] = fmaf(hs[s0 + 0], exp2f(dtv * A2[s0 + 0]), du * Bq.x);
      p0 = fmaf(hs[s0 + 0], Cq.x, p0);
      hs[s0 + 1] = fmaf(hs[s0 + 1], exp2f(dtv * A2[s0 + 1]), du * Bq.y);
      p1 = fmaf(hs[s0 + 1], Cq.y, p1);
      hs[s0 + 2] = fmaf(hs[s0 + 2], exp2f(dtv * A2[s0 + 2]), du * Bq.z);
      p2 = fmaf(hs[s0 + 2], Cq.z, p2);
      hs[s0 + 3] = fmaf(hs[s0 + 3], exp2f(dtv * A2[s0 + 3]), du * Bq.w);
      p3 = fmaf(hs[s0 + 3], Cq.w, p3);
    };
    upd(0, B0, C0); upd(4, B1, C1); upd(8, B2, C2); upd(12, B3, C3);
    float y = fmaf(Dpd, uu, (p0 + p1) + (p2 + p3));
    const float e = exp2f(-zz * 1.44269504f);
    y *= zz * __builtin_amdgcn_rcpf(1.f + e);
    ytile[t][lane] = f2bf(y);
  }
  __syncthreads();
  // coalesced row-major store: 4 lanes per time-row, 2 uint4 each
  const int row = lane >> 2;
  const int seg = (lane & 3) * 16;
  u16* dst =
      y16 + ((size_t)b * L_ + c * CHS + row) * DI + (g << 6) + seg;
  *(uint4*)dst = *(const uint4*)&ytile[row][seg];
  *(uint4*)(dst + 8) = *(const uint4*)&ytile[row][seg + 8];
}

// ---------------------------------------------------------------------------
// Final: rmsnorm(h[b, L-1, :]) @ w_fc + b_fc
// ---------------------------------------------------------------------------
__global__ __launch_bounds__(256) void final_kernel(
    const float* __restrict__ h, const float* __restrict__ fnw,
    const float* __restrict__ w_fc, const float* __restrict__ b_fc,
    float* __restrict__ out) {
  const int b = blockIdx.x;
  const int tid = threadIdx.x;
  const size_t row = ((size_t)b * L_ + (L_ - 1)) * DM;
  const float4 v = *(const float4*)(h + row + tid * 4);
  float ss = v.x * v.x + v.y * v.y + v.z * v.z + v.w * v.w;
#pragma unroll
  for (int off = 32; off > 0; off >>= 1) ss += __shfl_xor(ss, off);
  __shared__ float red[4];
  if ((tid & 63) == 0) red[tid >> 6] = ss;
  __syncthreads();
  float tot = red[0] + red[1] + red[2] + red[3];
  const float inv = rsqrtf(tot / (float)DM + EPS);
  const float4 wv = *(const float4*)(fnw + tid * 4);
  float hn[4] = {v.x * inv * wv.x, v.y * inv * wv.y, v.z * inv * wv.z,
                 v.w * inv * wv.w};
  float partial[NC];
#pragma unroll
  for (int j = 0; j < NC; j++) partial[j] = 0.f;
#pragma unroll
  for (int e = 0; e < 4; e++) {
    const int dd = tid * 4 + e;
#pragma unroll
    for (int j = 0; j < NC; j++)
      partial[j] = fmaf(hn[e], w_fc[dd * NC + j], partial[j]);
  }
  __shared__ float red2[256][NC];
  for (int j = 0; j < NC; j++) red2[tid][j] = partial[j];
  __syncthreads();
  for (int stride = 128; stride > 0; stride >>= 1) {
    if (tid < stride)
      for (int j = 0; j < NC; j++) red2[tid][j] += red2[tid + stride][j];
    __syncthreads();
  }
  if (tid < NC) out[b * NC + tid] = red2[0][tid] + b_fc[tid];
}

// ---------------------------------------------------------------------------
extern "C" void kernel_launch(void* const* d_in, const int* in_sizes, int n_in,
                              void* d_out, int out_size, void* d_ws,
                              size_t ws_size, hipStream_t stream) {
  const float* x = (const float*)d_in[0];
  const float* w_proj = (const float*)d_in[1];
  const float* b_proj = (const float*)d_in[2];
  const float* norm_w = (const float*)d_in[3];
  const float* w_in = (const float*)d_in[4];
  const float* w_conv = (const float*)d_in[5];
  const float* b_conv = (const float*)d_in[6];
  const float* w_x = (const float*)d_in[7];
  const float* w_dt = (const float*)d_in[8];
  const float* b_dt = (const float*)d_in[9];
  const float* A_log = (const float*)d_in[10];
  const float* Dp = (const float*)d_in[11];
  const float* w_out = (const float*)d_in[12];
  const float* fnw = (const float*)d_in[13];
  const float* w_fc = (const float*)d_in[14];
  const float* b_fc = (const float*)d_in[15];
  float* out = (float*)d_out;

  // Workspace layout (float units)
  float* ws = (float*)d_ws;
  float* h = ws;                               // 1,835,008
  float* p = h + 1835008;
  __half* xzT = (__half*)p;    p += 3670016;   // [4096][1792] fp16
  __half* uT = (__half*)p;     p += 1835008;   // [2048][1792] fp16
  __half* dtT = (__half*)p;    p += 1835008;   // [2048][1792] fp16
  float* xdblT = p;            p += 229376;    // [128][1792] fp32
  u16* y16 = (u16*)p;          p += 1835008;   // [1792][2048] bf16
  u16* xn16 = y16;                             // alias (disjoint liveness)
  u16* u16rm = (u16*)p;        p += 1835008;   // [1792][2048] bf16
  float* Sbuf = p;             p += 3670016;   // [14][8][2048][16] fp32
  float* sumdt = p;            p += 229376;    // [14][8][2048] fp32
  u16* x16 = (u16*)p;          p += 602112;
  u16* wprojT = (u16*)p;       p += 344064;
  u16* winT = (u16*)p;         p += 2097152;   // [4096][1024] bf16
  u16* woutT = (u16*)p;        p += 1048576;   // [1024][2048] bf16
  u16* w_x16 = (u16*)p;        p += 131072;    // [128][2048] bf16 (96 used)
  u16* w_dt16 = (u16*)p;       p += 65536;     // [2048][64] bf16
  u16* dtr16 = (u16*)p;        p += 57344;     // [1792][64] bf16

  const dim3 blk(256);

  cvt_kernel<<<ROWS * DLOC / 1024, blk, 0, stream>>>(x, x16);
  transpose_cvt_kernel<<<dim3(DM / 32, DLOC / 32), blk, 0, stream>>>(
      w_proj, wprojT, DLOC, DM);
  // h = b_proj (broadcast), then split-K atomic GEMM adds x @ w_proj
  init_bias_kernel<<<ROWS * DM / 1024, blk, 0, stream>>>(b_proj, h);

  // h += x @ w_proj  (split-K x3: 672 = 3*224, 336 blocks)
  gemm_bt_mfma<2, 0, 0, 0, 224, float>
      <<<dim3(DM / 128, ROWS / 128, 3), blk, 0, stream>>>(
          x16, wprojT, nullptr, h, 224, DLOC, DLOC, DM);

  for (int l = 0; l < NL; l++) {
    const float* Al = A_log + (size_t)l * DI * DS;
    // all weight transposes in one launch
    prep_weights_kernel<<<6464, blk, 0, stream>>>(
        w_in + (size_t)l * DM * 2 * DI, w_out + (size_t)l * DI * DM,
        w_x + (size_t)l * DI * 96, w_dt + (size_t)l * DR * DI, winT, woutT,
        w_x16, w_dt16);

    // xn = rmsnorm(h) -> bf16
    rmsnorm_kernel<<<ROWS, blk, 0, stream>>>(h, norm_w + (size_t)l * DM, xn16);
    // xzT[4096][1792] = (xn @ w_in[l])^T  (fp16, LDS-staged T epilogue)
    gemm_bt_mfma<0, 0, 1, 0, 0, __half>
        <<<dim3(2 * DI / 128, ROWS / 128), blk, 0, stream>>>(
            xn16, winT, nullptr, (__half*)xzT, DM, DM, DM, ROWS);
    // uT fp16 + u16rm bf16 = silu(conv(xpT) + b_conv)
    conv_silu_tile_kernel<<<dim3(DI / 32, ROWS / 32), blk, 0, stream>>>(
        xzT, w_conv + (size_t)l * DI * DC, b_conv + (size_t)l * DI, uT, u16rm);
    // xdblT[128][1792] = w_x16 @ u  (MFMA split-K x4, atomicAdd)
    hipMemsetAsync(xdblT, 0, (size_t)128 * ROWS * sizeof(float), stream);
    gemm_bt_mfma<2, 0, 0, 0, 512, float>
        <<<dim3(ROWS / 128, 1, 4), blk, 0, stream>>>(
            w_x16, u16rm, nullptr, xdblT, 512, DI, DI, ROWS);
    // dtr16[1792][64] = cvt(xdblT rows 0..63 ^T)
    transpose_cvt_kernel<<<dim3(ROWS / 32, DR / 32), blk, 0, stream>>>(
        xdblT, dtr16, DR, ROWS);
    // dtT[2048][1792] = softplus(w_dt16 @ dtr^T + b_dt[m]) -> fp16 (staged)
    gemm_bt_mfma<0, 2, 0, 1, 0, __half>
        <<<dim3(ROWS / 128, DI / 128), blk, 0, stream>>>(
            w_dt16, dtr16, b_dt + (size_t)l * DI, dtT, DR, DR, DR, ROWS);
    // parallel scan: local states -> combine -> apply (y16 row-major direct)
    scan_state_kernel<<<dim3(NCHK, DI / 64, B_), dim3(64), 0, stream>>>(
        dtT, uT, xdblT, Al, Sbuf, sumdt);
    scan_combine_kernel<<<B_ * DI * DS / 256, blk, 0, stream>>>(Sbuf, sumdt,
                                                                Al);
    scan_apply_kernel<<<dim3(NCHK, DI / 64, B_), dim3(64), 0, stream>>>(
        dtT, uT, xzT + (size_t)DI * ROWS, xdblT, Al, Dp + (size_t)l * DI,
        Sbuf, y16);
    // h += y @ w_out[l]  (split-K x4: 2048 = 4*512, 448 blocks, atomic)
    gemm_bt_mfma<2, 0, 0, 0, 512, float>
        <<<dim3(DM / 128, ROWS / 128, 4), blk, 0, stream>>>(
            y16, woutT, nullptr, h, 512, DI, DI, DM);
  }

  final_kernel<<<B_, blk, 0, stream>>>(h, fnw, w_fc, b_fc, out);
}

// Round 11
// 920.413 us; speedup vs baseline: 1.0183x; 1.0183x over previous
//
#include <hip/hip_runtime.h>
#include <hip/hip_bf16.h>
#include <hip/hip_fp16.h>
#include <math.h>

#define NL 4
#define DM 1024
#define DI 2048
#define DS 16
#define DR 64
#define DC 4
#define B_ 8
#define L_ 224
#define DLOC 672
#define NC 10
#define EPS 1e-5f

#define ROWS (B_ * L_)  // 1792
#define NCHK 14         // time chunks for parallel scan
#define CHS 16          // steps per chunk (14*16 = 224 = L_)

typedef unsigned short u16;
typedef __attribute__((ext_vector_type(8))) short bf16x8;
typedef __attribute__((ext_vector_type(4))) float f32x4;
typedef __attribute__((address_space(1))) const void gvoid_t;
typedef __attribute__((address_space(3))) void lvoid_t;

__device__ __forceinline__ u16 f2bf(float f) {
  union { float f; unsigned int u; } v;
  v.f = f;
  unsigned int u = v.u;
  return (u16)((u + 0x7fffu + ((u >> 16) & 1u)) >> 16);  // RNE
}

// load 4 consecutive halfs (8B aligned) -> 4 floats
__device__ __forceinline__ void load4h(const __half* p, float* o) {
  uint2 r = *(const uint2*)p;
  __half2 h0 = *(__half2*)&r.x;
  __half2 h1 = *(__half2*)&r.y;
  float2 f0 = __half22float2(h0);
  float2 f1 = __half22float2(h1);
  o[0] = f0.x; o[1] = f0.y; o[2] = f1.x; o[3] = f1.y;
}

// ---------------------------------------------------------------------------
// bf16 MFMA GEMM: C[M,N](+)=A[M,K]_bf16 @ Bt[N,K]_bf16^T. 128x128 tile.
// 2-phase pipeline, zero-asm: double-buffered LDS; STAGE(t+1) issued BEFORE
// computing tile t; single __syncthreads() per K-step (= vmcnt0+lgkm0+barrier)
// serves as both data-ready and buffer-free fence.
// ACC: 0=store, 1=+=, 2=atomicAdd(float). BROW: 0 none, 1 bias[n-col],
// 2 bias[m-row]. TSTORE=1: store C^T fp16 (OT=__half). ACT=1: softplus.
// SPLITK: nonzero = per-z K-chunk size in elements (K arg = chunk size).
// ---------------------------------------------------------------------------
template <int ACC, int BROW, int TSTORE, int ACT, int SPLITK, typename OT>
__global__ __launch_bounds__(256) void gemm_bt_mfma(
    const u16* __restrict__ A, const u16* __restrict__ Bt,
    const float* __restrict__ bias, OT* __restrict__ C, int K, int lda,
    int ldb, int ldc) {
  if (SPLITK) {
    A += (size_t)blockIdx.z * SPLITK;
    Bt += (size_t)blockIdx.z * SPLITK;
  }
  __shared__ __align__(16) u16 As[2][128 * 32];
  __shared__ __align__(16) u16 Bs[2][128 * 32];
  const int tid = threadIdx.x;
  const int lane = tid & 63;
  const int wv = tid >> 6;
  const int n0 = blockIdx.x * 128;
  const int m0 = blockIdx.y * 128;
  const int wm0 = (wv & 1) * 64;
  const int wn0 = (wv >> 1) * 64;
  const int quad = lane >> 4;
  const int l16 = lane & 15;

  const int srow = wv * 32 + (lane >> 2);
  const int scol = (lane & 3) * 8;
  const u16* ga0 = A + (size_t)(m0 + srow) * lda + scol;
  const u16* ga1 = ga0 + (size_t)16 * lda;
  const u16* gb0 = Bt + (size_t)(n0 + srow) * ldb + scol;
  const u16* gb1 = gb0 + (size_t)16 * ldb;
  const int lo0 = (wv * 32) * 32;
  const int lo1 = (wv * 32 + 16) * 32;

  f32x4 acc[4][4] = {};

  auto STAGE = [&](int buf, int kk) {
    __builtin_amdgcn_global_load_lds((gvoid_t*)(ga0 + kk),
                                     (lvoid_t*)&As[buf][lo0], 16, 0, 0);
    __builtin_amdgcn_global_load_lds((gvoid_t*)(ga1 + kk),
                                     (lvoid_t*)&As[buf][lo1], 16, 0, 0);
    __builtin_amdgcn_global_load_lds((gvoid_t*)(gb0 + kk),
                                     (lvoid_t*)&Bs[buf][lo0], 16, 0, 0);
    __builtin_amdgcn_global_load_lds((gvoid_t*)(gb1 + kk),
                                     (lvoid_t*)&Bs[buf][lo1], 16, 0, 0);
  };

  const int NT = K >> 5;
  STAGE(0, 0);
  __syncthreads();
  for (int t = 0; t < NT; ++t) {
    const int cur = t & 1;
    if (t + 1 < NT) STAGE(cur ^ 1, (t + 1) << 5);
    bf16x8 af[4], bfr[4];
#pragma unroll
    for (int i = 0; i < 4; i++)
      af[i] = *(const bf16x8*)&As[cur][(wm0 + i * 16 + l16) * 32 + quad * 8];
#pragma unroll
    for (int j = 0; j < 4; j++)
      bfr[j] = *(const bf16x8*)&Bs[cur][(wn0 + j * 16 + l16) * 32 + quad * 8];
#pragma unroll
    for (int i = 0; i < 4; i++)
#pragma unroll
      for (int j = 0; j < 4; j++)
        acc[i][j] = __builtin_amdgcn_mfma_f32_16x16x32_bf16(af[i], bfr[j],
                                                            acc[i][j], 0, 0, 0);
    // drains staged loads (overlapped with the MFMA above) + read-done fence
    __syncthreads();
  }

#pragma unroll
  for (int i = 0; i < 4; i++) {
#pragma unroll
    for (int j = 0; j < 4; j++) {
      const int col = n0 + wn0 + j * 16 + l16;
      const int rowb = m0 + wm0 + i * 16 + quad * 4;
      if (TSTORE) {
        __half* Ch = (__half*)C;
        union { __half2 h[2]; uint2 u; } pk;
        pk.h[0].x = __float2half(acc[i][j][0]);
        pk.h[0].y = __float2half(acc[i][j][1]);
        pk.h[1].x = __float2half(acc[i][j][2]);
        pk.h[1].y = __float2half(acc[i][j][3]);
        *(uint2*)(Ch + (size_t)col * ldc + rowb) = pk.u;
      } else {
        float bv = 0.f;
        if (BROW == 1) bv = bias[col];
#pragma unroll
        for (int r = 0; r < 4; r++) {
          float v = acc[i][j][r] + bv;
          if (BROW == 2) v += bias[rowb + r];
          if (ACT == 1) v = (v > 20.f) ? v : log1pf(expf(v));  // softplus
          OT* p = C + (size_t)(rowb + r) * ldc + col;
          if (ACC == 2) {
            atomicAdd((float*)p, v);
          } else {
            if (ACC == 1) v += (float)*p;
            *p = (OT)v;
          }
        }
      }
    }
  }
}

// ---------------------------------------------------------------------------
// fp32 [K,N] -> bf16 [N,K] transpose+convert (32x32 tiles)
// ---------------------------------------------------------------------------
__device__ __forceinline__ void transpose_cvt_body(
    const float* __restrict__ src, u16* __restrict__ dst, int K, int N,
    int bx, int by, int tid) {
  __shared__ float t[32][33];
  const int n0 = bx * 32;
  const int k0 = by * 32;
  const int c = tid & 31;
  const int r = tid >> 5;
#pragma unroll
  for (int rr = 0; rr < 4; rr++)
    t[r + rr * 8][c] = src[(size_t)(k0 + r + rr * 8) * N + n0 + c];
  __syncthreads();
#pragma unroll
  for (int rr = 0; rr < 4; rr++)
    dst[(size_t)(n0 + r + rr * 8) * K + k0 + c] = f2bf(t[c][r + rr * 8]);
}

__global__ __launch_bounds__(256) void transpose_cvt_kernel(
    const float* __restrict__ src, u16* __restrict__ dst, int K, int N) {
  transpose_cvt_body(src, dst, K, N, blockIdx.x, blockIdx.y, threadIdx.x);
}

// ---------------------------------------------------------------------------
// ONE upfront launch: x->bf16, wprojT, h=bias, and ALL 4 layers' weight
// transposes (per-layer destination buffers).
// blocks: [0,1176) x-cvt | [..+672) wprojT | [..+1792) h-init |
//         [..+4*6464) per-layer weight preps
// ---------------------------------------------------------------------------
__global__ __launch_bounds__(256) void prep_all_kernel(
    const float* __restrict__ x, const float* __restrict__ w_proj,
    const float* __restrict__ b_proj, const float* __restrict__ w_in,
    const float* __restrict__ w_out, const float* __restrict__ w_x,
    const float* __restrict__ w_dt, u16* __restrict__ x16,
    u16* __restrict__ wprojT, float* __restrict__ h, u16* __restrict__ winT,
    u16* __restrict__ woutT, u16* __restrict__ w_x16,
    u16* __restrict__ w_dt16) {
  int bid = blockIdx.x;
  const int tid = threadIdx.x;
  if (bid < 1176) {  // x -> bf16 (ROWS*DLOC/1024 blocks)
    const int i = bid * 256 + tid;
    const float4 v = ((const float4*)x)[i];
    ushort4 o;
    o.x = f2bf(v.x); o.y = f2bf(v.y); o.z = f2bf(v.z); o.w = f2bf(v.w);
    ((ushort4*)x16)[i] = o;
    return;
  }
  bid -= 1176;
  if (bid < 672) {  // wprojT[1024][672]
    transpose_cvt_body(w_proj, wprojT, DLOC, DM, bid & 31, bid >> 5, tid);
    return;
  }
  bid -= 672;
  if (bid < 1792) {  // h[row][col] = b_proj[col]
    const int i = bid * 256 + tid;
    const float4 v = ((const float4*)b_proj)[i & (DM / 4 - 1)];
    ((float4*)h)[i] = v;
    return;
  }
  bid -= 1792;
  const int l = bid / 6464;
  bid -= l * 6464;
  const float* w_in_l = w_in + (size_t)l * DM * 2 * DI;
  const float* w_out_l = w_out + (size_t)l * DI * DM;
  const float* w_x_l = w_x + (size_t)l * DI * 96;
  const float* w_dt_l = w_dt + (size_t)l * DR * DI;
  u16* winT_l = winT + (size_t)l * 4194304;
  u16* woutT_l = woutT + (size_t)l * 2097152;
  u16* w_x16_l = w_x16 + (size_t)l * 262144;
  u16* w_dt16_l = w_dt16 + (size_t)l * 131072;
  if (bid < 4096) {
    transpose_cvt_body(w_in_l, winT_l, DM, 2 * DI, bid & 127, bid >> 7, tid);
  } else if (bid < 6144) {
    bid -= 4096;
    transpose_cvt_body(w_out_l, woutT_l, DI, DM, bid & 31, bid >> 5, tid);
  } else if (bid < 6336) {
    bid -= 6144;
    transpose_cvt_body(w_x_l, w_x16_l, DI, 96, bid % 3, bid / 3, tid);
  } else {
    bid -= 6336;
    transpose_cvt_body(w_dt_l, w_dt16_l, DR, DI, bid & 63, bid >> 6, tid);
  }
}

// ---------------------------------------------------------------------------
// RMSNorm -> bf16
// ---------------------------------------------------------------------------
__global__ __launch_bounds__(256) void rmsnorm_kernel(
    const float* __restrict__ h, const float* __restrict__ w,
    u16* __restrict__ out) {
  const int row = blockIdx.x;
  const int tid = threadIdx.x;
  const float4 v = *(const float4*)(h + (size_t)row * DM + tid * 4);
  float ss = v.x * v.x + v.y * v.y + v.z * v.z + v.w * v.w;
#pragma unroll
  for (int off = 32; off > 0; off >>= 1) ss += __shfl_xor(ss, off);
  __shared__ float red[4];
  if ((tid & 63) == 0) red[tid >> 6] = ss;
  __syncthreads();
  float tot = red[0] + red[1] + red[2] + red[3];
  const float inv = rsqrtf(tot / (float)DM + EPS);
  const float4 wv = *(const float4*)(w + tid * 4);
  ushort4 o;
  o.x = f2bf(v.x * inv * wv.x);
  o.y = f2bf(v.y * inv * wv.y);
  o.z = f2bf(v.z * inv * wv.z);
  o.w = f2bf(v.w * inv * wv.w);
  *(ushort4*)(out + (size_t)row * DM + tid * 4) = o;
}

// ---------------------------------------------------------------------------
// Causal conv + bias + silu, 32x32 tile. Outputs BOTH:
//   uT fp16 [d][row] (for scan)  and  u16rm bf16 [row][d] (for w_x MFMA).
// ---------------------------------------------------------------------------
__global__ __launch_bounds__(256) void conv_silu_tile_kernel(
    const __half* __restrict__ xpT, const float* __restrict__ wc,
    const float* __restrict__ bc, __half* __restrict__ uT,
    u16* __restrict__ u16rm) {
  __shared__ u16 tile[32][33];  // [r-local][d-local] bf16
  const int tid = threadIdx.x;
  const int d0 = blockIdx.x * 32;
  const int r0 = blockIdx.y * 32;  // 32 | 224 => tile within one batch
  const int dl = tid >> 3;
  const int rq = (tid & 7) * 4;
  const int d = d0 + dl;
  const int r = r0 + rq;
  const int t = r % L_;
  const __half* row = xpT + (size_t)d * ROWS + r;
  float v[4];
  load4h(row, v);
  float p0 = 0.f, p1 = 0.f, p2 = 0.f;
  if (t > 0) {
    p0 = __half2float(row[-3]);
    p1 = __half2float(row[-2]);
    p2 = __half2float(row[-1]);
  }
  const float w0 = wc[d * 4 + 0], w1 = wc[d * 4 + 1], w2 = wc[d * 4 + 2],
              w3 = wc[d * 4 + 3];
  const float bb = bc[d];
  float o[4];
  float s;
  s = bb + p0 * w0 + p1 * w1 + p2 * w2 + v[0] * w3; o[0] = s / (1.f + expf(-s));
  s = bb + p1 * w0 + p2 * w1 + v[0] * w2 + v[1] * w3; o[1] = s / (1.f + expf(-s));
  s = bb + p2 * w0 + v[0] * w1 + v[1] * w2 + v[2] * w3; o[2] = s / (1.f + expf(-s));
  s = bb + v[0] * w0 + v[1] * w1 + v[2] * w2 + v[3] * w3; o[3] = s / (1.f + expf(-s));
  union { __half2 h[2]; uint2 u; } pk;
  pk.h[0].x = __float2half(o[0]); pk.h[0].y = __float2half(o[1]);
  pk.h[1].x = __float2half(o[2]); pk.h[1].y = __float2half(o[3]);
  *(uint2*)(uT + (size_t)d * ROWS + r) = pk.u;
#pragma unroll
  for (int i = 0; i < 4; i++) tile[rq + i][dl] = f2bf(o[i]);
  __syncthreads();
  const int rl = tid >> 3;
  const int dq = (tid & 7) * 4;
  ushort4 ov;
  ov.x = tile[rl][dq + 0];
  ov.y = tile[rl][dq + 1];
  ov.z = tile[rl][dq + 2];
  ov.w = tile[rl][dq + 3];
  *(ushort4*)(u16rm + (size_t)(r0 + rl) * DI + d0 + dq) = ov;
}

// ---------------------------------------------------------------------------
// Parallel linear scan, 3 phases, consuming TRANSPOSED tensors
// (dtT/uT/zT [d][row]: each lane's 16 timesteps are 32B contiguous).
// lane = channel (64 ch/wave), 16 states in registers, B/C broadcast via LDS.
// ---------------------------------------------------------------------------
__global__ __launch_bounds__(64) void scan_state_kernel(
    const __half* __restrict__ dtT, const __half* __restrict__ uT,
    const float* __restrict__ xdblT, const float* __restrict__ A_log,
    float* __restrict__ S, float* __restrict__ sumdt) {
  __shared__ float Bsh[CHS][20];  // [t][s], row stride 80B (16B-aligned)
  const int lane = threadIdx.x;
  const int c = blockIdx.x, g = blockIdx.y, b = blockIdx.z;
  const int d = (g << 6) + lane;
  const size_t tbase = (size_t)d * ROWS + (size_t)b * L_ + c * CHS;
  union HU { uint4 v[2]; __half h[16]; };
  HU dtb, ub;
  dtb.v[0] = *(const uint4*)(dtT + tbase);
  dtb.v[1] = *(const uint4*)(dtT + tbase + 8);
  ub.v[0] = *(const uint4*)(uT + tbase);
  ub.v[1] = *(const uint4*)(uT + tbase + 8);
  {
    const int s = lane >> 2, t0 = (lane & 3) * 4;
    const float4 bv = *(const float4*)(xdblT + (size_t)(DR + s) * ROWS +
                                       (size_t)b * L_ + c * CHS + t0);
    Bsh[t0 + 0][s] = bv.x;
    Bsh[t0 + 1][s] = bv.y;
    Bsh[t0 + 2][s] = bv.z;
    Bsh[t0 + 3][s] = bv.w;
  }
  float A2[DS];
  const float* al = A_log + (size_t)d * DS;
#pragma unroll
  for (int s = 0; s < DS; s++) A2[s] = -expf(al[s]) * 1.44269504f;
  __syncthreads();

  float hs[DS];
#pragma unroll
  for (int s = 0; s < DS; s++) hs[s] = 0.f;
  float cd = 0.f;
#pragma unroll
  for (int t = 0; t < CHS; t++) {
    const float dtv = __half2float(dtb.h[t]);
    const float uu = __half2float(ub.h[t]);
    const float du = dtv * uu;
    cd += dtv;
    const float4 B0 = *(const float4*)&Bsh[t][0];
    const float4 B1 = *(const float4*)&Bsh[t][4];
    const float4 B2 = *(const float4*)&Bsh[t][8];
    const float4 B3 = *(const float4*)&Bsh[t][12];
    auto upd = [&](int s0, float4 Bq) {
      hs[s0 + 0] = fmaf(hs[s0 + 0], exp2f(dtv * A2[s0 + 0]), du * Bq.x);
      hs[s0 + 1] = fmaf(hs[s0 + 1], exp2f(dtv * A2[s0 + 1]), du * Bq.y);
      hs[s0 + 2] = fmaf(hs[s0 + 2], exp2f(dtv * A2[s0 + 2]), du * Bq.z);
      hs[s0 + 3] = fmaf(hs[s0 + 3], exp2f(dtv * A2[s0 + 3]), du * Bq.w);
    };
    upd(0, B0); upd(4, B1); upd(8, B2); upd(12, B3);
  }
  float* Sp = S + (((size_t)c * B_ + b) * DI + d) * DS;
#pragma unroll
  for (int s = 0; s < DS; s++) Sp[s] = hs[s];
  sumdt[((size_t)c * B_ + b) * DI + d] = cd;
}

__global__ __launch_bounds__(256) void scan_combine_kernel(
    float* __restrict__ S, const float* __restrict__ sumdt,
    const float* __restrict__ A_log) {
  const int idx = blockIdx.x * 256 + threadIdx.x;  // B_*DI*DS threads
  const int s = idx & 15;
  const int d = (idx >> 4) & (DI - 1);
  const int b = idx >> 15;
  const float A2 = -expf(A_log[(size_t)d * DS + s]) * 1.44269504f;
  float hv = 0.f;
#pragma unroll
  for (int c = 0; c < NCHK; c++) {
    const size_t base = ((size_t)c * B_ + b) * DI + d;
    const size_t ix = base * DS + s;
    const float Sc = S[ix];
    const float Dc = exp2f(A2 * sumdt[base]);
    S[ix] = hv;  // hs_in for chunk c
    hv = fmaf(Dc, hv, Sc);
  }
}

__global__ __launch_bounds__(64) void scan_apply_kernel(
    const __half* __restrict__ dtT, const __half* __restrict__ uT,
    const __half* __restrict__ zT, const float* __restrict__ xdblT,
    const float* __restrict__ A_log, const float* __restrict__ Dp,
    const float* __restrict__ HS, u16* __restrict__ y16) {
  __shared__ float bcs[CHS][36];   // [t][s: 0..15=B, 16..31=C], 144B rows
  __shared__ u16 ytile[CHS][72];   // [t][d-local], padded
  const int lane = threadIdx.x;
  const int c = blockIdx.x, g = blockIdx.y, b = blockIdx.z;
  const int d = (g << 6) + lane;
  const size_t tbase = (size_t)d * ROWS + (size_t)b * L_ + c * CHS;
  union HU { uint4 v[2]; __half h[16]; };
  HU dtb, ub, zb;
  dtb.v[0] = *(const uint4*)(dtT + tbase);
  dtb.v[1] = *(const uint4*)(dtT + tbase + 8);
  ub.v[0] = *(const uint4*)(uT + tbase);
  ub.v[1] = *(const uint4*)(uT + tbase + 8);
  zb.v[0] = *(const uint4*)(zT + tbase);
  zb.v[1] = *(const uint4*)(zT + tbase + 8);
  {
    const int s = lane >> 1, t0 = (lane & 1) * 8;
    const float* src =
        xdblT + (size_t)(DR + s) * ROWS + (size_t)b * L_ + c * CHS + t0;
    const float4 v0 = *(const float4*)src;
    const float4 v1 = *(const float4*)(src + 4);
    bcs[t0 + 0][s] = v0.x; bcs[t0 + 1][s] = v0.y;
    bcs[t0 + 2][s] = v0.z; bcs[t0 + 3][s] = v0.w;
    bcs[t0 + 4][s] = v1.x; bcs[t0 + 5][s] = v1.y;
    bcs[t0 + 6][s] = v1.z; bcs[t0 + 7][s] = v1.w;
  }
  float A2[DS];
  const float* al = A_log + (size_t)d * DS;
#pragma unroll
  for (int s = 0; s < DS; s++) A2[s] = -expf(al[s]) * 1.44269504f;
  float hs[DS];
  const float* hp = HS + (((size_t)c * B_ + b) * DI + d) * DS;
#pragma unroll
  for (int s = 0; s < DS; s++) hs[s] = hp[s];
  const float Dpd = Dp[d];
  __syncthreads();

#pragma unroll
  for (int t = 0; t < CHS; t++) {
    const float dtv = __half2float(dtb.h[t]);
    const float uu = __half2float(ub.h[t]);
    const float zz = __half2float(zb.h[t]);
    const float du = dtv * uu;
    const float4 B0 = *(const float4*)&bcs[t][0];
    const float4 B1 = *(const float4*)&bcs[t][4];
    const float4 B2 = *(const float4*)&bcs[t][8];
    const float4 B3 = *(const float4*)&bcs[t][12];
    const float4 C0 = *(const float4*)&bcs[t][16];
    const float4 C1 = *(const float4*)&bcs[t][20];
    const float4 C2 = *(const float4*)&bcs[t][24];
    const float4 C3 = *(const float4*)&bcs[t][28];
    float p0 = 0.f, p1 = 0.f, p2 = 0.f, p3 = 0.f;
    auto upd = [&](int s0, float4 Bq, float4 Cq) {
      hs[s0 + 0] = fmaf(hs[s0 + 0], exp2f(dtv * A2[s0 + 0]), du * Bq.x);
      p0 = fmaf(hs[s0 + 0], Cq.x, p0);
      hs[s0 + 1] = fmaf(hs[s0 + 1], exp2f(dtv * A2[s0 + 1]), du * Bq.y);
      p1 = fmaf(hs[s0 + 1], Cq.y, p1);
      hs[s0 + 2] = fmaf(hs[s0 + 2], exp2f(dtv * A2[s0 + 2]), du * Bq.z);
      p2 = fmaf(hs[s0 + 2], Cq.z, p2);
      hs[s0 + 3] = fmaf(hs[s0 + 3], exp2f(dtv * A2[s0 + 3]), du * Bq.w);
      p3 = fmaf(hs[s0 + 3], Cq.w, p3);
    };
    upd(0, B0, C0); upd(4, B1, C1); upd(8, B2, C2); upd(12, B3, C3);
    float y = fmaf(Dpd, uu, (p0 + p1) + (p2 + p3));
    const float e = exp2f(-zz * 1.44269504f);
    y *= zz * __builtin_amdgcn_rcpf(1.f + e);
    ytile[t][lane] = f2bf(y);
  }
  __syncthreads();
  // coalesced row-major store: 4 lanes per time-row, 2 uint4 each
  const int row = lane >> 2;
  const int seg = (lane & 3) * 16;
  u16* dst =
      y16 + ((size_t)b * L_ + c * CHS + row) * DI + (g << 6) + seg;
  *(uint4*)dst = *(const uint4*)&ytile[row][seg];
  *(uint4*)(dst + 8) = *(const uint4*)&ytile[row][seg + 8];
}

// ---------------------------------------------------------------------------
// Final: rmsnorm(h[b, L-1, :]) @ w_fc + b_fc
// ---------------------------------------------------------------------------
__global__ __launch_bounds__(256) void final_kernel(
    const float* __restrict__ h, const float* __restrict__ fnw,
    const float* __restrict__ w_fc, const float* __restrict__ b_fc,
    float* __restrict__ out) {
  const int b = blockIdx.x;
  const int tid = threadIdx.x;
  const size_t row = ((size_t)b * L_ + (L_ - 1)) * DM;
  const float4 v = *(const float4*)(h + row + tid * 4);
  float ss = v.x * v.x + v.y * v.y + v.z * v.z + v.w * v.w;
#pragma unroll
  for (int off = 32; off > 0; off >>= 1) ss += __shfl_xor(ss, off);
  __shared__ float red[4];
  if ((tid & 63) == 0) red[tid >> 6] = ss;
  __syncthreads();
  float tot = red[0] + red[1] + red[2] + red[3];
  const float inv = rsqrtf(tot / (float)DM + EPS);
  const float4 wv = *(const float4*)(fnw + tid * 4);
  float hn[4] = {v.x * inv * wv.x, v.y * inv * wv.y, v.z * inv * wv.z,
                 v.w * inv * wv.w};
  float partial[NC];
#pragma unroll
  for (int j = 0; j < NC; j++) partial[j] = 0.f;
#pragma unroll
  for (int e = 0; e < 4; e++) {
    const int dd = tid * 4 + e;
#pragma unroll
    for (int j = 0; j < NC; j++)
      partial[j] = fmaf(hn[e], w_fc[dd * NC + j], partial[j]);
  }
  __shared__ float red2[256][NC];
  for (int j = 0; j < NC; j++) red2[tid][j] = partial[j];
  __syncthreads();
  for (int stride = 128; stride > 0; stride >>= 1) {
    if (tid < stride)
      for (int j = 0; j < NC; j++) red2[tid][j] += red2[tid + stride][j];
    __syncthreads();
  }
  if (tid < NC) out[b * NC + tid] = red2[0][tid] + b_fc[tid];
}

// ---------------------------------------------------------------------------
extern "C" void kernel_launch(void* const* d_in, const int* in_sizes, int n_in,
                              void* d_out, int out_size, void* d_ws,
                              size_t ws_size, hipStream_t stream) {
  const float* x = (const float*)d_in[0];
  const float* w_proj = (const float*)d_in[1];
  const float* b_proj = (const float*)d_in[2];
  const float* norm_w = (const float*)d_in[3];
  const float* w_in = (const float*)d_in[4];
  const float* w_conv = (const float*)d_in[5];
  const float* b_conv = (const float*)d_in[6];
  const float* w_x = (const float*)d_in[7];
  const float* w_dt = (const float*)d_in[8];
  const float* b_dt = (const float*)d_in[9];
  const float* A_log = (const float*)d_in[10];
  const float* Dp = (const float*)d_in[11];
  const float* w_out = (const float*)d_in[12];
  const float* fnw = (const float*)d_in[13];
  const float* w_fc = (const float*)d_in[14];
  const float* b_fc = (const float*)d_in[15];
  float* out = (float*)d_out;

  // Workspace layout (float units)
  float* ws = (float*)d_ws;
  float* h = ws;                               // 1,835,008
  float* p = h + 1835008;
  __half* xzT = (__half*)p;    p += 3670016;   // [4096][1792] fp16
  __half* uT = (__half*)p;     p += 1835008;   // [2048][1792] fp16
  __half* dtT = (__half*)p;    p += 1835008;   // [2048][1792] fp16
  float* xdblT = p;            p += 229376;    // [128][1792] fp32
  u16* y16 = (u16*)p;          p += 1835008;   // [1792][2048] bf16
  u16* xn16 = y16;                             // alias (disjoint liveness)
  u16* u16rm = (u16*)p;        p += 1835008;   // [1792][2048] bf16
  float* Sbuf = p;             p += 3670016;   // [14][8][2048][16] fp32
  float* sumdt = p;            p += 229376;    // [14][8][2048] fp32
  u16* x16 = (u16*)p;          p += 602112;
  u16* wprojT = (u16*)p;       p += 344064;
  u16* winT = (u16*)p;         p += 8388608;   // 4 x [4096][1024] bf16
  u16* woutT = (u16*)p;        p += 4194304;   // 4 x [1024][2048] bf16
  u16* w_x16 = (u16*)p;        p += 524288;    // 4 x [128][2048] bf16 (96 used)
  u16* w_dt16 = (u16*)p;       p += 262144;    // 4 x [2048][64] bf16
  u16* dtr16 = (u16*)p;        p += 57344;     // [1792][64] bf16

  const dim3 blk(256);

  // ALL prep in one saturated launch: x-cvt, wprojT, h=bias, 4x weight preps
  prep_all_kernel<<<1176 + 672 + 1792 + 4 * 6464, blk, 0, stream>>>(
      x, w_proj, b_proj, w_in, w_out, w_x, w_dt, x16, wprojT, h, winT, woutT,
      w_x16, w_dt16);

  // h += x @ w_proj  (split-K x3: 672 = 3*224, 336 blocks)
  gemm_bt_mfma<2, 0, 0, 0, 224, float>
      <<<dim3(DM / 128, ROWS / 128, 3), blk, 0, stream>>>(
          x16, wprojT, nullptr, h, 224, DLOC, DLOC, DM);

  for (int l = 0; l < NL; l++) {
    const float* Al = A_log + (size_t)l * DI * DS;
    const u16* winT_l = winT + (size_t)l * 4194304;
    const u16* woutT_l = woutT + (size_t)l * 2097152;
    const u16* w_x16_l = w_x16 + (size_t)l * 262144;
    const u16* w_dt16_l = w_dt16 + (size_t)l * 131072;

    // xn = rmsnorm(h) -> bf16
    rmsnorm_kernel<<<ROWS, blk, 0, stream>>>(h, norm_w + (size_t)l * DM, xn16);
    // xzT[4096][1792] = (xn @ w_in[l])^T  (fp16 T-store)
    gemm_bt_mfma<0, 0, 1, 0, 0, __half>
        <<<dim3(2 * DI / 128, ROWS / 128), blk, 0, stream>>>(
            xn16, winT_l, nullptr, (__half*)xzT, DM, DM, DM, ROWS);
    // uT fp16 + u16rm bf16 = silu(conv(xpT) + b_conv)
    conv_silu_tile_kernel<<<dim3(DI / 32, ROWS / 32), blk, 0, stream>>>(
        xzT, w_conv + (size_t)l * DI * DC, b_conv + (size_t)l * DI, uT, u16rm);
    // xdblT[128][1792] = w_x16 @ u  (MFMA split-K x4, atomicAdd)
    hipMemsetAsync(xdblT, 0, (size_t)128 * ROWS * sizeof(float), stream);
    gemm_bt_mfma<2, 0, 0, 0, 512, float>
        <<<dim3(ROWS / 128, 1, 4), blk, 0, stream>>>(
            w_x16_l, u16rm, nullptr, xdblT, 512, DI, DI, ROWS);
    // dtr16[1792][64] = cvt(xdblT rows 0..63 ^T)
    transpose_cvt_kernel<<<dim3(ROWS / 32, DR / 32), blk, 0, stream>>>(
        xdblT, dtr16, DR, ROWS);
    // dtT[2048][1792] = softplus(w_dt16 @ dtr^T + b_dt[m]) -> fp16
    gemm_bt_mfma<0, 2, 0, 1, 0, __half>
        <<<dim3(ROWS / 128, DI / 128), blk, 0, stream>>>(
            w_dt16_l, dtr16, b_dt + (size_t)l * DI, dtT, DR, DR, DR, ROWS);
    // parallel scan: local states -> combine -> apply (y16 row-major direct)
    scan_state_kernel<<<dim3(NCHK, DI / 64, B_), dim3(64), 0, stream>>>(
        dtT, uT, xdblT, Al, Sbuf, sumdt);
    scan_combine_kernel<<<B_ * DI * DS / 256, blk, 0, stream>>>(Sbuf, sumdt,
                                                                Al);
    scan_apply_kernel<<<dim3(NCHK, DI / 64, B_), dim3(64), 0, stream>>>(
        dtT, uT, xzT + (size_t)DI * ROWS, xdblT, Al, Dp + (size_t)l * DI,
        Sbuf, y16);
    // h += y @ w_out[l]  (split-K x4: 2048 = 4*512, 448 blocks, atomic)
    gemm_bt_mfma<2, 0, 0, 0, 512, float>
        <<<dim3(DM / 128, ROWS / 128, 4), blk, 0, stream>>>(
            y16, woutT_l, nullptr, h, 512, DI, DI, DM);
  }

  final_kernel<<<B_, blk, 0, stream>>>(h, fnw, w_fc, b_fc, out);
}